// Round 6
// baseline (203.027 us; speedup 1.0000x reference)
//
#include <hip/hip_runtime.h>

// VectorQuantizer — bit-exact replication of the fp32 numpy reference.
//   d = sum(z*z,1)[:,None] + sum(c*c,1)[None,:] - 2.0*einsum('nc,kc->nk',z,c)
// sums: numpy pairwise_sum n=64 (8 accumulators + fixed tree). einsum: AVX512
// order — 16 chained-FMA lanes over 4 blocks of 16, then reduce_add tree.
//
// Packing: adjacent CHANNELS (2c,2c+1) in one f2 -> v_pk_fma_f32 where the
// codebook operand is a contiguous even SGPR pair (no splat movs). Per-scalar
// operations and their order are bit-identical to the scalar version.
// Structure: 1 point/lane, 4-wave k-split (wave g: k in [128g,128g+128)),
// block = 64 points, 2048 blocks. Argmin over ascending disjoint k-ranges
// combined with strict < (first-occurrence preserved).

#pragma clang fp contract(off)

#define KCODES 512
#define CDIM 64
#define HW 4096              // 64*64
#define ZQ_ELEMS 8388608     // 32*64*64*64

typedef float f2 __attribute__((ext_vector_type(2)));

static __device__ __forceinline__ f2 pk_fma(f2 a, f2 b, f2 c) {
    return __builtin_elementwise_fma(a, b, c);
}

__global__ __launch_bounds__(256, 4) void vq_kernel(
    const float* __restrict__ z_e,
    const float* __restrict__ cb,
    float* __restrict__ out)
{
    __shared__ float cnorm[KCODES];
    __shared__ float dcand[4 * 64];
    __shared__ int   kcand[4 * 64];

    // np.sum(cb*cb, axis=1): pairwise_sum n=64 replica (products pre-rounded)
    for (int k = (int)threadIdx.x; k < KCODES; k += 256) {
        const float* row = cb + k * CDIM;
        float r[8];
        #pragma unroll
        for (int j = 0; j < 8; ++j) r[j] = row[j] * row[j];
        #pragma unroll
        for (int i = 8; i < 64; i += 8) {
            #pragma unroll
            for (int j = 0; j < 8; ++j) r[j] = r[j] + row[i + j] * row[i + j];
        }
        cnorm[k] = ((r[0] + r[1]) + (r[2] + r[3])) + ((r[4] + r[5]) + (r[6] + r[7]));
    }

    // block = 64 consecutive points; wave g covers k in [128g, 128g+128)
    const int lane = (int)threadIdx.x & 63;
    const int g = __builtin_amdgcn_readfirstlane((int)threadIdx.x >> 6);
    const int n0 = (int)blockIdx.x * 64;
    const int b = n0 / HW;
    const int hw0 = n0 % HW;
    const float* zp = z_e + (size_t)b * CDIM * HW + hw0 + lane;

    // one point per lane; channel pairs packed: zz2[m] = {z[2m], z[2m+1]}
    f2 zz2[CDIM / 2];
    #pragma unroll
    for (int m = 0; m < CDIM / 2; ++m) {
        f2 t;
        t.x = zp[(size_t)(2 * m) * HW];
        t.y = zp[(size_t)(2 * m + 1) * HW];
        zz2[m] = t;
    }

    // np.sum(z*z, axis=1): pairwise replica, packed by channel pairs.
    // pr[t] = {r[2t], r[2t+1]}; per-scalar ops identical to scalar version.
    float sz;
    {
        f2 pr[4];
        #pragma unroll
        for (int t = 0; t < 4; ++t) pr[t] = zz2[t] * zz2[t];
        #pragma unroll
        for (int i = 8; i < 64; i += 8) {
            #pragma unroll
            for (int t = 0; t < 4; ++t) {
                f2 zt = zz2[(i + 2 * t) / 2];
                pr[t] = pr[t] + zt * zt;
            }
        }
        float s01 = pr[0].x + pr[0].y;   // r0+r1
        float s23 = pr[1].x + pr[1].y;   // r2+r3
        float s45 = pr[2].x + pr[2].y;   // r4+r5
        float s67 = pr[3].x + pr[3].y;   // r6+r7
        sz = (s01 + s23) + (s45 + s67);
    }

    __syncthreads();

    float best = 3.4e38f;
    int bk = 0;
    const int k0 = g * 128;

    for (int i = 0; i < 128; ++i) {
        const int k = k0 + i;                  // wave-uniform -> s_load path
        const float* ck = cb + k * CDIM;

        // einsum AVX512 order, packed chains pv[j] = {v[2j], v[2j+1]}:
        // v[l] = fma(z[l],c[l], fma(z[16+l],c[16+l], fma(z[32+l],c[32+l],
        //        fma(z[48+l],c[48+l], 0))))
        f2 pv[8];
        #pragma unroll
        for (int j = 0; j < 8; ++j) {
            f2 c0 = *(const f2*)(ck + 2 * j);            // {c[2j],   c[2j+1]}
            f2 c1 = *(const f2*)(ck + 16 + 2 * j);       // {c[16+..],c[17+..]}
            f2 c2 = *(const f2*)(ck + 32 + 2 * j);
            f2 c3 = *(const f2*)(ck + 48 + 2 * j);
            f2 zero; zero.x = 0.f; zero.y = 0.f;
            pv[j] = pk_fma(zz2[j], c0,
                      pk_fma(zz2[8 + j], c1,
                        pk_fma(zz2[16 + j], c2,
                          pk_fma(zz2[24 + j], c3, zero))));
        }
        // reduce_add tree (packed): pe[j]={e[2j],e[2j+1]}, pf[j]={f[2j],f[2j+1]}
        f2 pe0 = pv[0] + pv[4], pe1 = pv[1] + pv[5];
        f2 pe2 = pv[2] + pv[6], pe3 = pv[3] + pv[7];
        f2 pf0 = pe0 + pe2, pf1 = pe1 + pe3;
        f2 pt = pf0 + pf1;                     // {f0+f2, f1+f3}
        float dot = pt.x + pt.y;               // (f0+f2) + (f1+f3)

        float A = sz + cnorm[k];               // fl(sz + sc_k)
        float d = A + dot * -2.f;              // fl(A - 2*dot), 2*dot exact

        if (d < best) { best = d; bk = k; }    // strict <: first occurrence
    }

    dcand[g * 64 + lane] = best;
    kcand[g * 64 + lane] = bk;
    __syncthreads();

    // combine over ascending k-ranges (strict < keeps first occurrence)
    float bd = dcand[lane];
    int bi = kcand[lane];
    #pragma unroll
    for (int gg = 1; gg < 4; ++gg) {
        float d2 = dcand[gg * 64 + lane];
        int   k2 = kcand[gg * 64 + lane];
        if (d2 < bd) { bd = d2; bi = k2; }
    }

    // indices (as float32, second output region) — wave 0 only
    if (g == 0) out[ZQ_ELEMS + n0 + lane] = (float)bi;

    // z_q: wave g writes channels [16g, 16g+16); coalesced 4B/lane stores
    const float* row = cb + (size_t)bi * CDIM;
    float* op = out + (size_t)b * CDIM * HW + hw0 + lane;
    #pragma unroll
    for (int c = 0; c < 16; ++c) {
        const int ch = g * 16 + c;
        op[(size_t)ch * HW] = row[ch];
    }
}

extern "C" void kernel_launch(void* const* d_in, const int* in_sizes, int n_in,
                              void* d_out, int out_size, void* d_ws, size_t ws_size,
                              hipStream_t stream) {
    const float* z_e = (const float*)d_in[0];
    const float* cb  = (const float*)d_in[1];
    float* out = (float*)d_out;
    vq_kernel<<<dim3(2048), dim3(256), 0, stream>>>(z_e, cb, out);
}

// Round 7
// 196.337 us; speedup vs baseline: 1.0341x; 1.0341x over previous
//
#include <hip/hip_runtime.h>
#include <stdint.h>

// VectorQuantizer — bit-exact replication of the fp32 numpy reference.
//   d = sum(z*z,1)[:,None] + sum(c*c,1)[None,:] - 2.0*einsum('nc,kc->nk',z,c)
// sums: numpy pairwise_sum n=64 (8 accumulators + fixed tree). einsum: AVX512
// order — 16 chained-FMA lanes over 4 blocks of 16, then reduce_add tree.
//
// Channel-pair packing (proven bit-exact in round 6) forced onto VOP3P via
// inline asm: v_pk_fma_f32 with z in VGPR pairs, codebook row in SGPR pairs
// (wave-uniform s_load path; 1 SGPR source per instr — legal), v_pk_add_f32
// for the reduce tree. Per-scalar ops and order identical to the scalar ref.
// Structure: 1 point/lane, 4-wave k-split (wave g: k in [128g,128g+128)),
// block = 64 points, 2048 blocks. Argmin over ascending disjoint k-ranges
// combined with strict < (first-occurrence preserved).

#pragma clang fp contract(off)

#define KCODES 512
#define CDIM 64
#define HW 4096              // 64*64
#define ZQ_ELEMS 8388608     // 32*64*64*64

typedef float f2 __attribute__((ext_vector_type(2)));

// d = {fma(a.x, b.lo, c.x), fma(a.y, b.hi, c.y)} — b is an SGPR pair
static __device__ __forceinline__ f2 pk_fma_s(f2 a, uint64_t b, f2 c) {
    f2 d;
    asm("v_pk_fma_f32 %0, %1, %2, %3" : "=v"(d) : "v"(a), "s"(b), "v"(c));
    return d;
}
static __device__ __forceinline__ f2 pk_add(f2 a, f2 b) {
    f2 d;
    asm("v_pk_add_f32 %0, %1, %2" : "=v"(d) : "v"(a), "v"(b));
    return d;
}

__global__ __launch_bounds__(256, 4) void vq_kernel(
    const float* __restrict__ z_e,
    const float* __restrict__ cb,
    float* __restrict__ out)
{
    __shared__ float cnorm[KCODES];
    __shared__ float dcand[4 * 64];
    __shared__ int   kcand[4 * 64];

    // np.sum(cb*cb, axis=1): pairwise_sum n=64 replica (products pre-rounded)
    for (int k = (int)threadIdx.x; k < KCODES; k += 256) {
        const float* row = cb + k * CDIM;
        float r[8];
        #pragma unroll
        for (int j = 0; j < 8; ++j) r[j] = row[j] * row[j];
        #pragma unroll
        for (int i = 8; i < 64; i += 8) {
            #pragma unroll
            for (int j = 0; j < 8; ++j) r[j] = r[j] + row[i + j] * row[i + j];
        }
        cnorm[k] = ((r[0] + r[1]) + (r[2] + r[3])) + ((r[4] + r[5]) + (r[6] + r[7]));
    }

    // block = 64 consecutive points; wave g covers k in [128g, 128g+128)
    const int lane = (int)threadIdx.x & 63;
    const int g = __builtin_amdgcn_readfirstlane((int)threadIdx.x >> 6);
    const int n0 = (int)blockIdx.x * 64;
    const int b = n0 / HW;
    const int hw0 = n0 % HW;
    const float* zp = z_e + (size_t)b * CDIM * HW + hw0 + lane;

    // one point per lane; channel pairs packed: zz2[m] = {z[2m], z[2m+1]}
    f2 zz2[CDIM / 2];
    #pragma unroll
    for (int m = 0; m < CDIM / 2; ++m) {
        f2 t;
        t.x = zp[(size_t)(2 * m) * HW];
        t.y = zp[(size_t)(2 * m + 1) * HW];
        zz2[m] = t;
    }

    // np.sum(z*z, axis=1): pairwise replica, packed by channel pairs
    // (plain C is fine here — runs once, not in the hot loop)
    float sz;
    {
        f2 pr[4];
        #pragma unroll
        for (int t = 0; t < 4; ++t) pr[t] = zz2[t] * zz2[t];
        #pragma unroll
        for (int i = 8; i < 64; i += 8) {
            #pragma unroll
            for (int t = 0; t < 4; ++t) {
                f2 zt = zz2[(i + 2 * t) / 2];
                pr[t] = pr[t] + zt * zt;
            }
        }
        float s01 = pr[0].x + pr[0].y;
        float s23 = pr[1].x + pr[1].y;
        float s45 = pr[2].x + pr[2].y;
        float s67 = pr[3].x + pr[3].y;
        sz = (s01 + s23) + (s45 + s67);
    }

    __syncthreads();

    f2 zero; zero.x = 0.f; zero.y = 0.f;   // hoisted VGPR pair for chain tails

    float best = 3.4e38f;
    int bk = 0;
    const int k0 = g * 128;

    for (int i = 0; i < 128; ++i) {
        const int k = k0 + i;                  // wave-uniform -> s_load path
        const float* ck = cb + k * CDIM;
        const uint64_t* cq = (const uint64_t*)(const void*)ck; // {c[2m],c[2m+1]} pairs

        // einsum AVX512 order, packed chains pv[j] = {v[2j], v[2j+1]}:
        // v[l] = fma(z[l],c[l], fma(z[16+l],c[16+l], fma(z[32+l],c[32+l],
        //        fma(z[48+l],c[48+l], 0))))
        f2 pv[8];
        #pragma unroll
        for (int j = 0; j < 8; ++j) {
            pv[j] = pk_fma_s(zz2[j], cq[j],
                      pk_fma_s(zz2[8 + j], cq[8 + j],
                        pk_fma_s(zz2[16 + j], cq[16 + j],
                          pk_fma_s(zz2[24 + j], cq[24 + j], zero))));
        }
        // reduce_add tree (packed): pe[j]={e[2j],e[2j+1]}, pf[j]={f[2j],f[2j+1]}
        f2 pe0 = pk_add(pv[0], pv[4]), pe1 = pk_add(pv[1], pv[5]);
        f2 pe2 = pk_add(pv[2], pv[6]), pe3 = pk_add(pv[3], pv[7]);
        f2 pf0 = pk_add(pe0, pe2), pf1 = pk_add(pe1, pe3);
        f2 pt = pk_add(pf0, pf1);              // {f0+f2, f1+f3}
        float dot = pt.x + pt.y;               // (f0+f2) + (f1+f3)

        float A = sz + cnorm[k];               // fl(sz + sc_k)
        float d = fmaf(dot, -2.f, A);          // == fl(A - 2*dot): 2*dot exact

        if (d < best) { best = d; bk = k; }    // strict <: first occurrence
    }

    dcand[g * 64 + lane] = best;
    kcand[g * 64 + lane] = bk;
    __syncthreads();

    // combine over ascending k-ranges (strict < keeps first occurrence)
    float bd = dcand[lane];
    int bi = kcand[lane];
    #pragma unroll
    for (int gg = 1; gg < 4; ++gg) {
        float d2 = dcand[gg * 64 + lane];
        int   k2 = kcand[gg * 64 + lane];
        if (d2 < bd) { bd = d2; bi = k2; }
    }

    // indices (as float32, second output region) — wave 0 only
    if (g == 0) out[ZQ_ELEMS + n0 + lane] = (float)bi;

    // z_q: wave g writes channels [16g, 16g+16); coalesced 4B/lane stores
    const float* row = cb + (size_t)bi * CDIM;
    float* op = out + (size_t)b * CDIM * HW + hw0 + lane;
    #pragma unroll
    for (int c = 0; c < 16; ++c) {
        const int ch = g * 16 + c;
        op[(size_t)ch * HW] = row[ch];
    }
}

extern "C" void kernel_launch(void* const* d_in, const int* in_sizes, int n_in,
                              void* d_out, int out_size, void* d_ws, size_t ws_size,
                              hipStream_t stream) {
    const float* z_e = (const float*)d_in[0];
    const float* cb  = (const float*)d_in[1];
    float* out = (float*)d_out;
    vq_kernel<<<dim3(2048), dim3(256), 0, stream>>>(z_e, cb, out);
}